// Round 1
// baseline (916.222 us; speedup 1.0000x reference)
//
#include <hip/hip_runtime.h>
#include <math.h>

#define TOKENS 16384   // B*S = 4*4096
#define DDIM   4096
#define NEXP   128
#define TOPK   8
#define BK     64
#define BKP    68      // padded LDS row stride (floats): 68*4B=272B -> 2-way conflicts only
#define TM     64      // tokens per workgroup

__global__ __launch_bounds__(256, 1)
void router_kernel(const float* __restrict__ x,
                   const float* __restrict__ W,
                   const float* __restrict__ b,
                   float* __restrict__ out)
{
    // 64 KB LDS, reused: phase 1 = fp32 tiles (52.2 KB), phase 2 = fp64 logits (64 KB)
    __shared__ __align__(16) char smem[TM * NEXP * 8];
    float*  xs = (float*)smem;                 // [TM][BKP]
    float*  ws = (float*)smem + TM * BKP;      // [NEXP][BKP]
    double* lg = (double*)smem;                // [TM][NEXP]

    const int t    = threadIdx.x;
    const int wg   = blockIdx.x;
    const int tok0 = wg * TM;

    const int el  = t & 15;    // expert-lane: experts el + 16*j
    const int tg  = t >> 4;    // token-group: tokens  tg*4 + i
    const int sub = t >> 4;    // staging row-sub
    const int q4  = (t & 15) * 4;  // staging col (floats)

    double acc[4][8];
    #pragma unroll
    for (int i = 0; i < 4; ++i)
        #pragma unroll
        for (int j = 0; j < 8; ++j) acc[i][j] = 0.0;

    float4 gx[4], gw[8];

    // ---- prefetch chunk 0 ----
    {
        const int k0 = 0;
        #pragma unroll
        for (int i = 0; i < 4; ++i)
            gx[i] = *reinterpret_cast<const float4*>(
                &x[(size_t)(tok0 + i * 16 + sub) * DDIM + k0 + q4]);
        #pragma unroll
        for (int j = 0; j < 8; ++j)
            gw[j] = *reinterpret_cast<const float4*>(
                &W[(size_t)(j * 16 + sub) * DDIM + k0 + q4]);
    }

    // ---- K loop: 64 chunks of BK=64 ----
    #pragma unroll 1
    for (int c = 0; c < DDIM / BK; ++c) {
        __syncthreads();
        // stage regs -> LDS
        #pragma unroll
        for (int i = 0; i < 4; ++i)
            *reinterpret_cast<float4*>(&xs[(i * 16 + sub) * BKP + q4]) = gx[i];
        #pragma unroll
        for (int j = 0; j < 8; ++j)
            *reinterpret_cast<float4*>(&ws[(j * 16 + sub) * BKP + q4]) = gw[j];
        __syncthreads();

        // issue next chunk's global loads (hidden under the FMA block)
        if (c + 1 < DDIM / BK) {
            const int k0 = (c + 1) * BK;
            #pragma unroll
            for (int i = 0; i < 4; ++i)
                gx[i] = *reinterpret_cast<const float4*>(
                    &x[(size_t)(tok0 + i * 16 + sub) * DDIM + k0 + q4]);
            #pragma unroll
            for (int j = 0; j < 8; ++j)
                gw[j] = *reinterpret_cast<const float4*>(
                    &W[(size_t)(j * 16 + sub) * DDIM + k0 + q4]);
        }

        // compute: fp64 accumulate
        #pragma unroll 2
        for (int kk = 0; kk < BK; kk += 4) {
            float4 xa[4], wb[8];
            #pragma unroll
            for (int i = 0; i < 4; ++i)
                xa[i] = *reinterpret_cast<const float4*>(&xs[(tg * 4 + i) * BKP + kk]);
            #pragma unroll
            for (int j = 0; j < 8; ++j)
                wb[j] = *reinterpret_cast<const float4*>(&ws[(el + 16 * j) * BKP + kk]);
            #pragma unroll
            for (int i = 0; i < 4; ++i) {
                #pragma unroll
                for (int j = 0; j < 8; ++j) {
                    acc[i][j] = fma((double)xa[i].x, (double)wb[j].x, acc[i][j]);
                    acc[i][j] = fma((double)xa[i].y, (double)wb[j].y, acc[i][j]);
                    acc[i][j] = fma((double)xa[i].z, (double)wb[j].z, acc[i][j]);
                    acc[i][j] = fma((double)xa[i].w, (double)wb[j].w, acc[i][j]);
                }
            }
        }
    }

    // ---- logits to LDS (reuse tile memory) ----
    __syncthreads();
    #pragma unroll
    for (int i = 0; i < 4; ++i)
        #pragma unroll
        for (int j = 0; j < 8; ++j)
            lg[(tg * 4 + i) * NEXP + (el + 16 * j)] = acc[i][j];
    __syncthreads();

    // ---- per-wave softmax + top-8 ----
    const int lane = t & 63;
    const int wv   = t >> 6;   // 4 waves, 16 tokens each

    for (int it = 0; it < TM / 4; ++it) {
        const int m = wv * 16 + it;
        const int e1 = lane, e2 = lane + 64;
        double v1 = lg[m * NEXP + e1] + (double)b[e1];
        double v2 = lg[m * NEXP + e2] + (double)b[e2];

        // wave max (butterfly -> all lanes)
        double mx = fmax(v1, v2);
        #pragma unroll
        for (int off = 32; off > 0; off >>= 1)
            mx = fmax(mx, __shfl_xor(mx, off, 64));

        // softmax denominator over ALL experts
        double s = exp(v1 - mx) + exp(v2 - mx);
        #pragma unroll
        for (int off = 32; off > 0; off >>= 1)
            s += __shfl_xor(s, off, 64);

        // 8 rounds of argmax; tie -> lower index (matches jax.lax.top_k)
        double w1 = v1, w2 = v2;
        for (int r = 0; r < TOPK; ++r) {
            double bv = w1; int bi = e1;
            if (w2 > bv) { bv = w2; bi = e2; }   // e2>e1, so tie keeps e1
            #pragma unroll
            for (int off = 32; off > 0; off >>= 1) {
                double ov = __shfl_xor(bv, off, 64);
                int    oi = __shfl_xor(bi, off, 64);
                if (ov > bv || (ov == bv && oi < bi)) { bv = ov; bi = oi; }
            }
            if (lane == 0) {
                const size_t T = (size_t)tok0 + m;
                out[T * TOPK + r] = (float)(exp(bv - mx) / s);
                out[(size_t)TOKENS * TOPK + T * TOPK + r] = (float)bi;
            }
            if (bi == e1) w1 = -1e300;
            if (bi == e2) w2 = -1e300;
        }
    }
}

extern "C" void kernel_launch(void* const* d_in, const int* in_sizes, int n_in,
                              void* d_out, int out_size, void* d_ws, size_t ws_size,
                              hipStream_t stream) {
    const float* x = (const float*)d_in[0];
    const float* W = (const float*)d_in[1];
    const float* b = (const float*)d_in[2];
    float* out = (float*)d_out;

    dim3 grid(TOKENS / TM);   // 256 workgroups
    dim3 block(256);
    hipLaunchKernelGGL(router_kernel, grid, block, 0, stream, x, W, b, out);
}